// Round 9
// baseline (18.791 us; speedup 1.0000x reference)
//
#include <hip/hip_runtime.h>

#define SIZE_IN   8192
#define SIZE_OUT  2048
#define CH        128                // i's per split
#define NSPLIT    (SIZE_IN / CH)     // 64 splits -> ws = 512 KiB
#define JT        2                  // j tiles per split
#define JTILE     (SIZE_OUT / JT)    // 1024 floats
#define BLOCK     256

typedef float f4 __attribute__((ext_vector_type(4)));

// Kernel 1: block = (i-chunk, j-half). Thread owns one float4 of j.
// Plain cached loads (nt regressed: weight set is cache-warm across replays).
// Grid = 128 blocks: R6->R8 trend shows fewer, longer blocks win (memory-
// system-bound, not CU-issue-bound); 128 CUs x 4 waves still covers the
// needed 49 GB/s/CU with ~5x headroom.
__global__ __launch_bounds__(BLOCK) void ill_partial(
    const float* __restrict__ x,
    const int*   __restrict__ idx,
    const float* __restrict__ w,
    float*       __restrict__ ws)
{
    const int jt  = blockIdx.x & (JT - 1);
    const int ic  = blockIdx.x / JT;
    const int tid = threadIdx.x;
    const int j   = jt * JTILE + tid * 4;
    const int i0  = ic * CH;

    f4 acc = (f4)(0.f);

    #pragma unroll
    for (int k = 0; k < CH; ++k) {
        const int    i  = i0 + k;              // wave-uniform -> scalar path
        const float  xv = x[i];
        const size_t q  = (size_t)idx[i];
        const f4 wv = *reinterpret_cast<const f4*>(
            w + ((q << 13) + (size_t)i) * (size_t)SIZE_OUT + j);
        acc += xv * wv;
    }

    *reinterpret_cast<f4*>(ws + (size_t)ic * SIZE_OUT + j) = acc;
}

// Kernel 2: one WAVE per f4 column; NSPLIT=64 -> lane l owns row l exactly:
// one load + shfl tree. Grid = 128 blocks (512 waves).
__global__ __launch_bounds__(BLOCK) void ill_reduce(
    const float* __restrict__ ws,
    const float* __restrict__ bias,
    float*       __restrict__ out)
{
    const int lane = threadIdx.x & 63;
    const int j4   = blockIdx.x * (BLOCK / 64) + (threadIdx.x >> 6);
    const f4* ws4  = reinterpret_cast<const f4*>(ws);

    f4 acc = ws4[(size_t)lane * (SIZE_OUT / 4) + j4];

    #pragma unroll
    for (int off = 32; off > 0; off >>= 1) {
        acc.x += __shfl_down(acc.x, off, 64);
        acc.y += __shfl_down(acc.y, off, 64);
        acc.z += __shfl_down(acc.z, off, 64);
        acc.w += __shfl_down(acc.w, off, 64);
    }

    if (lane == 0) {
        acc += reinterpret_cast<const f4*>(bias)[j4];
        *reinterpret_cast<f4*>(reinterpret_cast<float*>(out) + j4 * 4) = acc;
    }
}

extern "C" void kernel_launch(void* const* d_in, const int* in_sizes, int n_in,
                              void* d_out, int out_size, void* d_ws, size_t ws_size,
                              hipStream_t stream) {
    const float* x    = (const float*)d_in[0];
    const int*   idx  = (const int*)d_in[1];
    const float* w    = (const float*)d_in[2];
    const float* bias = (const float*)d_in[3];
    float* out = (float*)d_out;
    float* ws  = (float*)d_ws;

    ill_partial<<<dim3(NSPLIT * JT), dim3(BLOCK), 0, stream>>>(x, idx, w, ws);
    ill_reduce<<<dim3((SIZE_OUT / 4) / (BLOCK / 64)), dim3(BLOCK), 0, stream>>>(
        ws, bias, out);
}

// Round 10
// 17.907 us; speedup vs baseline: 1.0494x; 1.0494x over previous
//
#include <hip/hip_runtime.h>

#define SIZE_IN   8192
#define SIZE_OUT  2048
#define CH        64                 // i's per split  (measured knee: R8 optimum)
#define NSPLIT    (SIZE_IN / CH)     // 128 splits -> ws = 1 MiB
#define JT        2                  // j tiles per split
#define JTILE     (SIZE_OUT / JT)    // 1024 floats
#define BLOCK     256

typedef float f4 __attribute__((ext_vector_type(4)));

// Kernel 1: block = (i-chunk, j-half). Thread owns one float4 of j.
// Plain cached loads (nt regressed: weight set is cache-warm across replays).
// Grid = 256 blocks = 1/CU. CH sweep measured: 16->21.3us, 32->19.0, 64->17.7,
// 128->18.8 (half the CUs idle) => CH=64 is the knee.
__global__ __launch_bounds__(BLOCK) void ill_partial(
    const float* __restrict__ x,
    const int*   __restrict__ idx,
    const float* __restrict__ w,
    float*       __restrict__ ws)
{
    const int jt  = blockIdx.x & (JT - 1);
    const int ic  = blockIdx.x / JT;
    const int tid = threadIdx.x;
    const int j   = jt * JTILE + tid * 4;
    const int i0  = ic * CH;

    f4 acc = (f4)(0.f);

    #pragma unroll
    for (int k = 0; k < CH; ++k) {
        const int    i  = i0 + k;              // wave-uniform -> scalar path
        const float  xv = x[i];
        const size_t q  = (size_t)idx[i];
        const f4 wv = *reinterpret_cast<const f4*>(
            w + ((q << 13) + (size_t)i) * (size_t)SIZE_OUT + j);
        acc += xv * wv;
    }

    *reinterpret_cast<f4*>(ws + (size_t)ic * SIZE_OUT + j) = acc;
}

// Kernel 2: one WAVE per f4 column. Lane l sums rows {l, l+64}; shfl tree;
// lane 0 adds bias and writes. Grid = 128 blocks (512 waves).
__global__ __launch_bounds__(BLOCK) void ill_reduce(
    const float* __restrict__ ws,
    const float* __restrict__ bias,
    float*       __restrict__ out)
{
    const int lane = threadIdx.x & 63;
    const int j4   = blockIdx.x * (BLOCK / 64) + (threadIdx.x >> 6);
    const f4* ws4  = reinterpret_cast<const f4*>(ws);

    f4 acc = (f4)(0.f);
    #pragma unroll
    for (int r = 0; r < NSPLIT / 64; ++r) {
        acc += ws4[(size_t)(r * 64 + lane) * (SIZE_OUT / 4) + j4];
    }

    #pragma unroll
    for (int off = 32; off > 0; off >>= 1) {
        acc.x += __shfl_down(acc.x, off, 64);
        acc.y += __shfl_down(acc.y, off, 64);
        acc.z += __shfl_down(acc.z, off, 64);
        acc.w += __shfl_down(acc.w, off, 64);
    }

    if (lane == 0) {
        acc += reinterpret_cast<const f4*>(bias)[j4];
        *reinterpret_cast<f4*>(reinterpret_cast<float*>(out) + j4 * 4) = acc;
    }
}

extern "C" void kernel_launch(void* const* d_in, const int* in_sizes, int n_in,
                              void* d_out, int out_size, void* d_ws, size_t ws_size,
                              hipStream_t stream) {
    const float* x    = (const float*)d_in[0];
    const int*   idx  = (const int*)d_in[1];
    const float* w    = (const float*)d_in[2];
    const float* bias = (const float*)d_in[3];
    float* out = (float*)d_out;
    float* ws  = (float*)d_ws;

    ill_partial<<<dim3(NSPLIT * JT), dim3(BLOCK), 0, stream>>>(x, idx, w, ws);
    ill_reduce<<<dim3((SIZE_OUT / 4) / (BLOCK / 64)), dim3(BLOCK), 0, stream>>>(
        ws, bias, out);
}